// Round 4
// baseline (270.321 us; speedup 1.0000x reference)
//
#include <hip/hip_runtime.h>
#include <stdint.h>

using f32x4  = __attribute__((ext_vector_type(4))) float;
using bf16x8 = __attribute__((ext_vector_type(8))) short;
using ushort8 = __attribute__((ext_vector_type(8))) unsigned short;

#define B_   16384
#define S_   256
#define DIN  2048
#define DFC  1024
#define NB_  10

// f32 -> bf16 round-to-nearest-even
__device__ __forceinline__ unsigned short f2bf(float f) {
  union { float f; unsigned int u; } v; v.f = f;
  unsigned int u = v.u;
  unsigned int r = (u + 0x7FFFu + ((u >> 16) & 1u)) >> 16;
  return (unsigned short)r;
}

// async global->LDS, 16B per lane. LDS dest is wave-uniform base + lane*16.
__device__ __forceinline__ void gload_lds16(const void* g, void* l) {
  __builtin_amdgcn_global_load_lds(
      (const __attribute__((address_space(1))) unsigned int*)g,
      (__attribute__((address_space(3))) unsigned int*)l, 16, 0, 0);
}

// ---------------- K0a: W1 (f32, [K=2048][N=1024]) -> Wt (bf16, [N][K]) ----------------
__global__ __launch_bounds__(256)
void convT_kernel(const float* __restrict__ W, unsigned short* __restrict__ Wt) {
  __shared__ unsigned short t[32][33];
  const int tx = threadIdx.x & 31;
  const int ty = threadIdx.x >> 5;          // 0..7
  const int nb = blockIdx.x * 32;           // n base
  const int kb = blockIdx.y * 32;           // k base
#pragma unroll
  for (int i = 0; i < 32; i += 8)
    t[ty + i][tx] = f2bf(W[(size_t)(kb + ty + i) * DFC + nb + tx]);
  __syncthreads();
#pragma unroll
  for (int i = 0; i < 32; i += 8)
    Wt[(size_t)(nb + ty + i) * DIN + kb + tx] = t[tx][ty + i];
}

// ---------------- K0b: A (f32 [16384][2048]) -> Ab (bf16, same layout) ----------------
__global__ __launch_bounds__(256)
void convA_kernel(const float* __restrict__ A, unsigned short* __restrict__ Ab) {
  const size_t total = (size_t)B_ * DIN;
  size_t idx = ((size_t)blockIdx.x * 256 + threadIdx.x) * 8;
  const size_t stride = (size_t)gridDim.x * 256 * 8;
  for (; idx < total; idx += stride) {
    f32x4 a = *(const f32x4*)(A + idx);
    f32x4 b = *(const f32x4*)(A + idx + 4);
    ushort8 o;
    o[0] = f2bf(a[0]); o[1] = f2bf(a[1]); o[2] = f2bf(a[2]); o[3] = f2bf(a[3]);
    o[4] = f2bf(b[0]); o[5] = f2bf(b[1]); o[6] = f2bf(b[2]); o[7] = f2bf(b[3]);
    *(ushort8*)(Ab + idx) = o;
  }
}

// ---------------- K1: x = elu(Ab @ Wt^T + b1), stored bf16 ----------------
// 256x256 tile, 8 waves (2M x 4N), BK=64 K-tiles (32 of them), 4 phases/tile,
// 16 MFMA + 1 barrier per phase, counted vmcnt(8), setprio around MFMA.
// LDS: sT[dbuf][op][kslice] = 16KB slice of [256 rows][32 cols] packed as
// 128 lrows x 8 chunks(16B); chunk p of lrow holds (row=lrow*2+q>>2, kc=q&3)
// with q = p ^ (lrow&7) -> conflict-free ds_read_b128, linear gload_lds dest.
__global__ __launch_bounds__(512, 2)
void gemm1_kernel(const unsigned short* __restrict__ Ab, const unsigned short* __restrict__ Bt,
                  const float* __restrict__ b1, unsigned short* __restrict__ X) {
  __shared__ unsigned short sT[2][2][2][8192];  // [dbuf][A=0/B=1][ks] 128KB
  const int tid  = threadIdx.x;
  const int wave = tid >> 6, lane = tid & 63;
  const int wm = wave >> 2, wn = wave & 3;      // 2M x 4N waves, wave tile 128x64
  const int b = blockIdx.x;                     // 256 blocks
  const int tile = (b & 7) * 32 + (b >> 3);     // XCD-chunked bijection
  const int mtile = tile >> 2, ntile = tile & 3;
  const int rowBase = mtile * 256, colBase = ntile * 256;

  f32x4 acc[8][4] = {};

  // staging source (inverse swizzle)
  const int lrow0 = wave * 16 + (lane >> 3);    // +8 for instr j=1 (same &7)
  const int q     = (lane & 7) ^ (lrow0 & 7);
  const unsigned short* gA = Ab + (size_t)(rowBase + lrow0 * 2 + (q >> 2)) * DIN + (q & 3) * 8;
  const unsigned short* gB = Bt + (size_t)(colBase + lrow0 * 2 + (q >> 2)) * DIN + (q & 3) * 8;
  const int ldOff = wave * 1024;

  // fragment read offsets
  const int frow = lane & 15, hi = lane >> 4, fr2 = frow >> 1;
  const int pp    = ((frow & 1) * 4 + hi) ^ (fr2 & 7);
  const int aBase = (wm * 64 + fr2) * 64 + pp * 8;   // + mf*512
  const int bBase = (wn * 32 + fr2) * 64 + pp * 8;   // + nf*512

#define STAGE(opv, db, ksv, kt) do {                                        \
    const unsigned short* g_ = ((opv) ? gB : gA) + (kt) * 64 + (ksv) * 32;  \
    unsigned short* l_ = &sT[db][opv][ksv][ldOff];                          \
    gload_lds16(g_, l_);                                                    \
    gload_lds16(g_ + (size_t)16 * DIN, l_ + 512);                           \
  } while (0)

  bf16x8 afr[4], bfr[4];
#define READ_B(db, ksv) do {                                                \
    const unsigned short* s_ = &sT[db][1][ksv][bBase];                      \
    bfr[0] = *(const bf16x8*)(s_);        bfr[1] = *(const bf16x8*)(s_ + 512); \
    bfr[2] = *(const bf16x8*)(s_ + 1024); bfr[3] = *(const bf16x8*)(s_ + 1536); \
  } while (0)
#define READ_A(db, ksv, mq) do {                                            \
    const unsigned short* s_ = &sT[db][0][ksv][aBase + (mq) * 2048];        \
    afr[0] = *(const bf16x8*)(s_);        afr[1] = *(const bf16x8*)(s_ + 512); \
    afr[2] = *(const bf16x8*)(s_ + 1024); afr[3] = *(const bf16x8*)(s_ + 1536); \
  } while (0)
#define MFMA16(mq) do {                                                     \
    __builtin_amdgcn_s_setprio(1);                                          \
    _Pragma("unroll") for (int m_ = 0; m_ < 4; ++m_)                        \
      _Pragma("unroll") for (int n_ = 0; n_ < 4; ++n_)                      \
        acc[(mq) * 4 + m_][n_] = __builtin_amdgcn_mfma_f32_16x16x32_bf16(   \
            afr[m_], bfr[n_], acc[(mq) * 4 + m_][n_], 0, 0, 0);             \
    __builtin_amdgcn_s_setprio(0);                                          \
  } while (0)
#define FENCE asm volatile("" ::: "memory")
#define BAR do { FENCE; __builtin_amdgcn_s_barrier(); FENCE; } while (0)

  // prologue: tile0 all 4 slices, tile1 ks0 slices (12 loads/thread)
  STAGE(0, 0, 0, 0); STAGE(1, 0, 0, 0); STAGE(0, 0, 1, 0); STAGE(1, 0, 1, 0);
  STAGE(0, 1, 0, 1); STAGE(1, 1, 0, 1);

  const int NT = DIN / 64;  // 32
#pragma unroll 2
  for (int k = 0; k < NT - 1; ++k) {
    const int db = k & 1, dn = db ^ 1;
    // P1: compute (ks0, mq0) ; stage Aks1(k+1)
    asm volatile("s_waitcnt vmcnt(8)" ::: "memory");
    BAR;
    READ_B(db, 0); READ_A(db, 0, 0);
    STAGE(0, dn, 1, k + 1);
    MFMA16(0);
    // P2: (ks0, mq1) ; stage Bks1(k+1)
    BAR;
    READ_A(db, 0, 1);
    STAGE(1, dn, 1, k + 1);
    MFMA16(1);
    // P3: (ks1, mq0) ; stage Aks0(k+2)
    asm volatile("s_waitcnt vmcnt(8)" ::: "memory");
    BAR;
    READ_B(db, 1); READ_A(db, 1, 0);
    if (k < NT - 2) STAGE(0, db, 0, k + 2);
    MFMA16(0);
    // P4: (ks1, mq1) ; stage Bks0(k+2)
    BAR;
    READ_A(db, 1, 1);
    if (k < NT - 2) STAGE(1, db, 0, k + 2);
    MFMA16(1);
  }
  {  // peeled last tile (k = NT-1, db = 1)
    const int db = (NT - 1) & 1;
    asm volatile("s_waitcnt vmcnt(4)" ::: "memory");
    BAR;
    READ_B(db, 0); READ_A(db, 0, 0);
    MFMA16(0);
    BAR;
    READ_A(db, 0, 1);
    MFMA16(1);
    asm volatile("s_waitcnt vmcnt(0)" ::: "memory");
    BAR;
    READ_B(db, 1); READ_A(db, 1, 0);
    MFMA16(0);
    BAR;
    READ_A(db, 1, 1);
    MFMA16(1);
  }
#undef STAGE
#undef READ_A
#undef READ_B
#undef MFMA16

  // epilogue: C/D layout col = lane&15, row = (lane>>4)*4 + reg
  const int er0 = rowBase + wm * 128 + hi * 4;
  const int ec0 = colBase + wn * 64 + frow;
  float bv[4];
#pragma unroll
  for (int n = 0; n < 4; ++n) bv[n] = b1[ec0 + n * 16];
#pragma unroll
  for (int m = 0; m < 8; ++m)
#pragma unroll
    for (int n = 0; n < 4; ++n)
#pragma unroll
      for (int r = 0; r < 4; ++r) {
        float v = acc[m][n][r] + bv[n];
        v = v > 0.f ? v : expm1f(v);
        X[(size_t)(er0 + m * 16 + r) * DFC + ec0 + n * 16] = f2bf(v);
      }
}

// ---------------- K2: fused shape_params + sampling ----------------
// Per 64-row block: GEMM (x @ w_shape + b_shape) -> write mode/log_std to out
// and mode/exp(log_std) to LDS -> sample 64 rows x 256 x 10 from noise.
__global__ __launch_bounds__(256)
void gemm2_sample_kernel(const unsigned short* __restrict__ X, const float* __restrict__ Wsh,
                         const float* __restrict__ bsh, const float* __restrict__ noise,
                         float* __restrict__ out) {
  __shared__ unsigned short sX[64 * 32];    // linear for global_load_lds
  __shared__ unsigned short sW[32 * 40];    // [j][k] stride 40 (80B)
  __shared__ float smode[64][NB_];
  __shared__ float sexp[64][NB_];
  const int tid  = threadIdx.x;
  const int wave = tid >> 6, lane = tid & 63;
  const int rowB = blockIdx.x * 64;
  f32x4 acc[2] = {};
  const unsigned short* xp = X + (size_t)(rowB + (tid >> 2)) * DFC + (tid & 3) * 8;
  unsigned short* sXb = &sX[wave * 512];
  const int frow = lane & 15, fks = (lane >> 4) * 8;

  for (int kk = 0; kk < DFC; kk += 32) {
    gload_lds16(xp + kk, sXb);
    for (int idx = tid; idx < 32 * 40; idx += 256) {
      int j = idx / 40, ki = idx - j * 40;
      sW[idx] = (j < 20 && ki < 32) ? f2bf(Wsh[(size_t)(kk + ki) * 20 + j]) : (unsigned short)0;
    }
    __syncthreads();
    bf16x8 xa  = *(const bf16x8*)&sX[(wave * 16 + frow) * 32 + fks];
    bf16x8 w0  = *(const bf16x8*)&sW[(frow) * 40 + fks];
    bf16x8 w1f = *(const bf16x8*)&sW[(16 + frow) * 40 + fks];
    acc[0] = __builtin_amdgcn_mfma_f32_16x16x32_bf16(xa, w0,  acc[0], 0, 0, 0);
    acc[1] = __builtin_amdgcn_mfma_f32_16x16x32_bf16(xa, w1f, acc[1], 0, 0, 0);
    __syncthreads();
  }
  const int r0l = wave * 16 + (lane >> 4) * 4;  // local row 0..63
  const int c0 = lane & 15;
#pragma unroll
  for (int n = 0; n < 2; ++n) {
    int j = n * 16 + c0;
    if (j < 20) {
      float bj = bsh[j];
      int jj = j < 10 ? j : j - 10;
      size_t base = (j < 10) ? (size_t)0 : (size_t)B_ * NB_;
#pragma unroll
      for (int r = 0; r < 4; ++r) {
        float val = acc[n][r] + bj;
        out[base + (size_t)(rowB + r0l + r) * NB_ + jj] = val;
        if (j < 10) smode[r0l + r][jj] = val;
        else        sexp[r0l + r][jj]  = expf(val);
      }
    }
  }
  __syncthreads();
  // sampling: wave handles local rows wave*16 .. +15
  for (int i = 0; i < 16; ++i) {
    const int lr = wave * 16 + i;
    const size_t nb = (size_t)(rowB + lr) * (S_ * NB_);
    const f32x4* np4 = (const f32x4*)(noise + nb);
    f32x4*       op4 = (f32x4*)(out + (size_t)2 * B_ * NB_ + nb);
#pragma unroll
    for (int it = 0; it < 10; ++it) {
      f32x4 nv = np4[it * 64 + lane];
      int j0 = (lane * 4 + it * 6) % 10;
      int j1 = j0 + 1; if (j1 >= 10) j1 -= 10;
      int j2 = j1 + 1; if (j2 >= 10) j2 -= 10;
      int j3 = j2 + 1; if (j3 >= 10) j3 -= 10;
      f32x4 r;
      r[0] = smode[lr][j0] + sexp[lr][j0] * nv[0];
      r[1] = smode[lr][j1] + sexp[lr][j1] * nv[1];
      r[2] = smode[lr][j2] + sexp[lr][j2] * nv[2];
      r[3] = smode[lr][j3] + sexp[lr][j3] * nv[3];
      op4[it * 64 + lane] = r;
    }
  }
}

extern "C" void kernel_launch(void* const* d_in, const int* in_sizes, int n_in,
                              void* d_out, int out_size, void* d_ws, size_t ws_size,
                              hipStream_t stream) {
  const float* A     = (const float*)d_in[0];  // [16384][2048]
  const float* W1    = (const float*)d_in[1];  // [2048][1024]
  const float* b1    = (const float*)d_in[2];  // [1024]
  const float* Wsh   = (const float*)d_in[3];  // [1024][20]
  const float* bsh   = (const float*)d_in[4];  // [20]
  const float* noise = (const float*)d_in[5];  // [16384][256][10]
  float* out = (float*)d_out;                  // mode | log_std | samples

  unsigned short* Wt = (unsigned short*)d_ws;                      // bf16 [1024][2048] = 4 MB
  unsigned short* X  = (unsigned short*)d_ws + (size_t)DFC * DIN;  // bf16 [16384][1024] = 33.5 MB
  // Ab (bf16 A, 64 MB): ws if it fits, else stash in d_out's samples region
  // (written before gemm1 reads it, overwritten by gemm2_sample at the end).
  const size_t wsNeed = (size_t)DFC * DIN * 2 + (size_t)B_ * DFC * 2 + (size_t)B_ * DIN * 2;
  unsigned short* Ab = (ws_size >= wsNeed)
      ? (unsigned short*)d_ws + (size_t)DFC * DIN + (size_t)B_ * DFC
      : (unsigned short*)(out + (size_t)2 * B_ * NB_);

  convT_kernel<<<dim3(DFC / 32, DIN / 32), 256, 0, stream>>>(W1, Wt);
  convA_kernel<<<dim3(2048), 256, 0, stream>>>(A, Ab);
  gemm1_kernel<<<dim3((B_ / 256) * (DFC / 256)), 512, 0, stream>>>(Ab, Wt, b1, X);
  gemm2_sample_kernel<<<dim3(B_ / 64), 256, 0, stream>>>(X, Wsh, bsh, noise, out);
}

// Round 5
// 217.086 us; speedup vs baseline: 1.2452x; 1.2452x over previous
//
#include <hip/hip_runtime.h>
#include <stdint.h>

using f32x4  = __attribute__((ext_vector_type(4))) float;
using bf16x8 = __attribute__((ext_vector_type(8))) short;
using ushort8 = __attribute__((ext_vector_type(8))) unsigned short;

#define B_   16384
#define S_   256
#define DIN  2048
#define DFC  1024
#define NB_  10

// f32 -> bf16 round-to-nearest-even
__device__ __forceinline__ unsigned short f2bf(float f) {
  union { float f; unsigned int u; } v; v.f = f;
  unsigned int u = v.u;
  unsigned int r = (u + 0x7FFFu + ((u >> 16) & 1u)) >> 16;
  return (unsigned short)r;
}

// async global->LDS, 16B per lane. LDS dest is wave-uniform base + lane*16.
__device__ __forceinline__ void gload_lds16(const void* g, void* l) {
  __builtin_amdgcn_global_load_lds(
      (const __attribute__((address_space(1))) unsigned int*)g,
      (__attribute__((address_space(3))) unsigned int*)l, 16, 0, 0);
}

// ---------------- K0a: W1 (f32, [K=2048][N=1024]) -> Wt (bf16, [N][K]) ----------------
__global__ __launch_bounds__(256)
void convT_kernel(const float* __restrict__ W, unsigned short* __restrict__ Wt) {
  __shared__ unsigned short t[32][33];
  const int tx = threadIdx.x & 31;
  const int ty = threadIdx.x >> 5;          // 0..7
  const int nb = blockIdx.x * 32;           // n base
  const int kb = blockIdx.y * 32;           // k base
#pragma unroll
  for (int i = 0; i < 32; i += 8)
    t[ty + i][tx] = f2bf(W[(size_t)(kb + ty + i) * DFC + nb + tx]);
  __syncthreads();
#pragma unroll
  for (int i = 0; i < 32; i += 8)
    Wt[(size_t)(nb + ty + i) * DIN + kb + tx] = t[tx][ty + i];
}

// ---------------- K0b: A (f32 [16384][2048]) -> Ab (bf16, same layout) ----------------
__global__ __launch_bounds__(256)
void convA_kernel(const float* __restrict__ A, unsigned short* __restrict__ Ab) {
  const size_t total = (size_t)B_ * DIN;
  size_t idx = ((size_t)blockIdx.x * 256 + threadIdx.x) * 8;
  const size_t stride = (size_t)gridDim.x * 256 * 8;
  for (; idx < total; idx += stride) {
    f32x4 a = *(const f32x4*)(A + idx);
    f32x4 b = *(const f32x4*)(A + idx + 4);
    ushort8 o;
    o[0] = f2bf(a[0]); o[1] = f2bf(a[1]); o[2] = f2bf(a[2]); o[3] = f2bf(a[3]);
    o[4] = f2bf(b[0]); o[5] = f2bf(b[1]); o[6] = f2bf(b[2]); o[7] = f2bf(b[3]);
    *(ushort8*)(Ab + idx) = o;
  }
}

// ---------------- K1: x = elu(Ab @ Wt^T + b1), stored bf16 ----------------
// 256x256 tile, 8 waves (2M x 4N), BK=64 K-tiles (32 of them), 4 phases/tile,
// 16 MFMA + 1 barrier per phase, counted vmcnt(8), setprio around MFMA.
__global__ __launch_bounds__(512, 2)
void gemm1_kernel(const unsigned short* __restrict__ Ab, const unsigned short* __restrict__ Bt,
                  const float* __restrict__ b1, unsigned short* __restrict__ X) {
  __shared__ unsigned short sT[2][2][2][8192];  // [dbuf][A=0/B=1][ks] 128KB
  const int tid  = threadIdx.x;
  const int wave = tid >> 6, lane = tid & 63;
  const int wm = wave >> 2, wn = wave & 3;      // 2M x 4N waves, wave tile 128x64
  const int b = blockIdx.x;                     // 256 blocks
  const int tile = (b & 7) * 32 + (b >> 3);     // XCD-chunked bijection
  const int mtile = tile >> 2, ntile = tile & 3;
  const int rowBase = mtile * 256, colBase = ntile * 256;

  f32x4 acc[8][4] = {};

  // staging source (inverse swizzle)
  const int lrow0 = wave * 16 + (lane >> 3);    // +8 for instr j=1 (same &7)
  const int q     = (lane & 7) ^ (lrow0 & 7);
  const unsigned short* gA = Ab + (size_t)(rowBase + lrow0 * 2 + (q >> 2)) * DIN + (q & 3) * 8;
  const unsigned short* gB = Bt + (size_t)(colBase + lrow0 * 2 + (q >> 2)) * DIN + (q & 3) * 8;
  const int ldOff = wave * 1024;

  // fragment read offsets
  const int frow = lane & 15, hi = lane >> 4, fr2 = frow >> 1;
  const int pp    = ((frow & 1) * 4 + hi) ^ (fr2 & 7);
  const int aBase = (wm * 64 + fr2) * 64 + pp * 8;   // + mf*512
  const int bBase = (wn * 32 + fr2) * 64 + pp * 8;   // + nf*512

#define STAGE(opv, db, ksv, kt) do {                                        \
    const unsigned short* g_ = ((opv) ? gB : gA) + (kt) * 64 + (ksv) * 32;  \
    unsigned short* l_ = &sT[db][opv][ksv][ldOff];                          \
    gload_lds16(g_, l_);                                                    \
    gload_lds16(g_ + (size_t)16 * DIN, l_ + 512);                           \
  } while (0)

  bf16x8 afr[4], bfr[4];
#define READ_B(db, ksv) do {                                                \
    const unsigned short* s_ = &sT[db][1][ksv][bBase];                      \
    bfr[0] = *(const bf16x8*)(s_);        bfr[1] = *(const bf16x8*)(s_ + 512); \
    bfr[2] = *(const bf16x8*)(s_ + 1024); bfr[3] = *(const bf16x8*)(s_ + 1536); \
  } while (0)
#define READ_A(db, ksv, mq) do {                                            \
    const unsigned short* s_ = &sT[db][0][ksv][aBase + (mq) * 2048];        \
    afr[0] = *(const bf16x8*)(s_);        afr[1] = *(const bf16x8*)(s_ + 512); \
    afr[2] = *(const bf16x8*)(s_ + 1024); afr[3] = *(const bf16x8*)(s_ + 1536); \
  } while (0)
#define MFMA16(mq) do {                                                     \
    __builtin_amdgcn_s_setprio(1);                                          \
    _Pragma("unroll") for (int m_ = 0; m_ < 4; ++m_)                        \
      _Pragma("unroll") for (int n_ = 0; n_ < 4; ++n_)                      \
        acc[(mq) * 4 + m_][n_] = __builtin_amdgcn_mfma_f32_16x16x32_bf16(   \
            afr[m_], bfr[n_], acc[(mq) * 4 + m_][n_], 0, 0, 0);             \
    __builtin_amdgcn_s_setprio(0);                                          \
  } while (0)
#define FENCE asm volatile("" ::: "memory")
#define BAR do { FENCE; __builtin_amdgcn_s_barrier(); FENCE; } while (0)

  // prologue: tile0 all 4 slices, tile1 ks0 slices (12 loads/thread)
  STAGE(0, 0, 0, 0); STAGE(1, 0, 0, 0); STAGE(0, 0, 1, 0); STAGE(1, 0, 1, 0);
  STAGE(0, 1, 0, 1); STAGE(1, 1, 0, 1);

  const int NT = DIN / 64;  // 32
#pragma unroll 2
  for (int k = 0; k < NT - 1; ++k) {
    const int db = k & 1, dn = db ^ 1;
    // P1: compute (ks0, mq0) ; stage Aks1(k+1)
    asm volatile("s_waitcnt vmcnt(8)" ::: "memory");
    BAR;
    READ_B(db, 0); READ_A(db, 0, 0);
    STAGE(0, dn, 1, k + 1);
    MFMA16(0);
    // P2: (ks0, mq1) ; stage Bks1(k+1)
    BAR;
    READ_A(db, 0, 1);
    STAGE(1, dn, 1, k + 1);
    MFMA16(1);
    // P3: (ks1, mq0) ; stage Aks0(k+2)
    asm volatile("s_waitcnt vmcnt(8)" ::: "memory");
    BAR;
    READ_B(db, 1); READ_A(db, 1, 0);
    if (k < NT - 2) STAGE(0, db, 0, k + 2);
    MFMA16(0);
    // P4: (ks1, mq1) ; stage Bks0(k+2)
    BAR;
    READ_A(db, 1, 1);
    if (k < NT - 2) STAGE(1, db, 0, k + 2);
    MFMA16(1);
  }
  {  // peeled last tile (k = NT-1, db = 1)
    const int db = (NT - 1) & 1;
    asm volatile("s_waitcnt vmcnt(4)" ::: "memory");
    BAR;
    READ_B(db, 0); READ_A(db, 0, 0);
    MFMA16(0);
    BAR;
    READ_A(db, 0, 1);
    MFMA16(1);
    asm volatile("s_waitcnt vmcnt(0)" ::: "memory");
    BAR;
    READ_B(db, 1); READ_A(db, 1, 0);
    MFMA16(0);
    BAR;
    READ_A(db, 1, 1);
    MFMA16(1);
  }
#undef STAGE
#undef READ_A
#undef READ_B
#undef MFMA16

  // epilogue: C/D layout col = lane&15, row = (lane>>4)*4 + reg
  const int er0 = rowBase + wm * 128 + hi * 4;
  const int ec0 = colBase + wn * 64 + frow;
  float bv[4];
#pragma unroll
  for (int n = 0; n < 4; ++n) bv[n] = b1[ec0 + n * 16];
#pragma unroll
  for (int m = 0; m < 8; ++m)
#pragma unroll
    for (int n = 0; n < 4; ++n)
#pragma unroll
      for (int r = 0; r < 4; ++r) {
        float v = acc[m][n][r] + bv[n];
        v = v > 0.f ? v : expm1f(v);
        X[(size_t)(er0 + m * 16 + r) * DFC + ec0 + n * 16] = f2bf(v);
      }
}

// ---------------- K2: shape_params = x @ w_shape + b_shape -> d_out (mode | log_std) ----------------
__global__ __launch_bounds__(256)
void gemm2_kernel(const unsigned short* __restrict__ X, const float* __restrict__ Wsh,
                  const float* __restrict__ bsh, float* __restrict__ out) {
  __shared__ unsigned short sX[64 * 32];    // linear for global_load_lds
  __shared__ unsigned short sW[32 * 40];    // [j][k] stride 40 (80B)
  const int tid  = threadIdx.x;
  const int wave = tid >> 6, lane = tid & 63;
  const int rowB = blockIdx.x * 64;
  f32x4 acc[2] = {};
  const unsigned short* xp = X + (size_t)(rowB + (tid >> 2)) * DFC + (tid & 3) * 8;
  unsigned short* sXb = &sX[wave * 512];
  const int frow = lane & 15, fks = (lane >> 4) * 8;

  for (int kk = 0; kk < DFC; kk += 32) {
    gload_lds16(xp + kk, sXb);
    for (int idx = tid; idx < 32 * 40; idx += 256) {
      int j = idx / 40, ki = idx - j * 40;
      sW[idx] = (j < 20 && ki < 32) ? f2bf(Wsh[(size_t)(kk + ki) * 20 + j]) : (unsigned short)0;
    }
    __syncthreads();
    bf16x8 xa  = *(const bf16x8*)&sX[(wave * 16 + frow) * 32 + fks];
    bf16x8 w0  = *(const bf16x8*)&sW[(frow) * 40 + fks];
    bf16x8 w1f = *(const bf16x8*)&sW[(16 + frow) * 40 + fks];
    acc[0] = __builtin_amdgcn_mfma_f32_16x16x32_bf16(xa, w0,  acc[0], 0, 0, 0);
    acc[1] = __builtin_amdgcn_mfma_f32_16x16x32_bf16(xa, w1f, acc[1], 0, 0, 0);
    __syncthreads();
  }
  const int r0 = rowB + wave * 16 + (lane >> 4) * 4;
  const int c0 = lane & 15;
#pragma unroll
  for (int n = 0; n < 2; ++n) {
    int j = n * 16 + c0;
    if (j < 20) {
      float bj = bsh[j];
      int jj = j < 10 ? j : j - 10;
      size_t base = (j < 10) ? (size_t)0 : (size_t)B_ * NB_;
#pragma unroll
      for (int r = 0; r < 4; ++r)
        out[base + (size_t)(r0 + r) * NB_ + jj] = acc[n][r] + bj;
    }
  }
}

// ---------------- K3: samples = mode + exp(log_std) * noise ----------------
// one wave per row; float4 loads/stores; mode/exp(ls) broadcast from tiny LDS arrays.
__global__ __launch_bounds__(256)
void sample_kernel(const float* __restrict__ noise, float* __restrict__ out) {
  __shared__ float sm[4][NB_], se[4][NB_];
  const int tid  = threadIdx.x;
  const int wave = tid >> 6, lane = tid & 63;
  const int row  = blockIdx.x * 4 + wave;
  if (lane < NB_) {
    sm[wave][lane] = out[(size_t)row * NB_ + lane];
    se[wave][lane] = expf(out[(size_t)B_ * NB_ + (size_t)row * NB_ + lane]);
  }
  __syncthreads();
  const f32x4* np4 = (const f32x4*)(noise + (size_t)row * (S_ * NB_));
  f32x4*       op4 = (f32x4*)(out + (size_t)2 * B_ * NB_ + (size_t)row * (S_ * NB_));
#pragma unroll
  for (int it = 0; it < (S_ * NB_) / 256; ++it) {   // 10 iters
    f32x4 nv = np4[it * 64 + lane];
    int j0 = (lane * 4 + it * 6) % 10;
    int j1 = j0 + 1; if (j1 >= 10) j1 -= 10;
    int j2 = j1 + 1; if (j2 >= 10) j2 -= 10;
    int j3 = j2 + 1; if (j3 >= 10) j3 -= 10;
    f32x4 r;
    r[0] = sm[wave][j0] + se[wave][j0] * nv[0];
    r[1] = sm[wave][j1] + se[wave][j1] * nv[1];
    r[2] = sm[wave][j2] + se[wave][j2] * nv[2];
    r[3] = sm[wave][j3] + se[wave][j3] * nv[3];
    op4[it * 64 + lane] = r;
  }
}

extern "C" void kernel_launch(void* const* d_in, const int* in_sizes, int n_in,
                              void* d_out, int out_size, void* d_ws, size_t ws_size,
                              hipStream_t stream) {
  const float* A     = (const float*)d_in[0];  // [16384][2048]
  const float* W1    = (const float*)d_in[1];  // [2048][1024]
  const float* b1    = (const float*)d_in[2];  // [1024]
  const float* Wsh   = (const float*)d_in[3];  // [1024][20]
  const float* bsh   = (const float*)d_in[4];  // [20]
  const float* noise = (const float*)d_in[5];  // [16384][256][10]
  float* out = (float*)d_out;                  // mode | log_std | samples

  unsigned short* Wt = (unsigned short*)d_ws;                      // bf16 [1024][2048] = 4 MB
  unsigned short* X  = (unsigned short*)d_ws + (size_t)DFC * DIN;  // bf16 [16384][1024] = 33.5 MB
  // Ab (bf16 A, 64 MB): ws if it fits, else stash in d_out's samples region
  // (written before gemm1 reads it, overwritten by sample_kernel at the end).
  const size_t wsNeed = (size_t)DFC * DIN * 2 + (size_t)B_ * DFC * 2 + (size_t)B_ * DIN * 2;
  unsigned short* Ab = (ws_size >= wsNeed)
      ? (unsigned short*)d_ws + (size_t)DFC * DIN + (size_t)B_ * DFC
      : (unsigned short*)(out + (size_t)2 * B_ * NB_);

  convT_kernel<<<dim3(DFC / 32, DIN / 32), 256, 0, stream>>>(W1, Wt);
  convA_kernel<<<dim3(2048), 256, 0, stream>>>(A, Ab);
  gemm1_kernel<<<dim3((B_ / 256) * (DFC / 256)), 512, 0, stream>>>(Ab, Wt, b1, X);
  gemm2_kernel<<<dim3(B_ / 64), 256, 0, stream>>>(X, Wsh, bsh, out);
  sample_kernel<<<dim3(B_ / 4), 256, 0, stream>>>(noise, out);
}